// Round 2
// baseline (5624.866 us; speedup 1.0000x reference)
//
#include <hip/hip_runtime.h>
#include <hip/hip_bf16.h>

// Seq2Seq (batch=1): enc LSTM (S=256) -> dec LSTM (T=256, teacher forcing)
// -> linear (VOUT=32000) -> log_softmax.
//
// v3 == v2 (unbenched: broker capacity) + formal memory-model hardening of
// the grid barrier (__threadfence before publish). Structure:
//   1) input_gemm: gates_x[t][r] = dot(emb[tok(t)], Wih[r]) + bih[r] + bhh[r]
//   2) lstm_seq: ONE persistent kernel, 512 steps, Whh in registers
//      (128 f32 VGPRs/thread), device-scope atomic grid barrier per step
//   3) out_gemm: logits = Hs @ lin_W^T + b (MFMA bf16)
//   4) log_softmax per row

#define HDIM 1024
#define SLEN 256
#define TLEN 256
#define VOUTN 32000
#define G4 4096
#define NWGC 128      // workgroups in persistent kernel (<=256 CUs -> co-resident)
#define HPW 8         // hidden indices per WG = 1024/128

typedef __bf16 bf16_t;
typedef __bf16 bf16x8 __attribute__((ext_vector_type(8)));
typedef float f32x4 __attribute__((ext_vector_type(4)));

static __device__ inline bf16x8 cvt8(float4 a, float4 b) {
    bf16x8 r;
    r[0] = (__bf16)a.x; r[1] = (__bf16)a.y; r[2] = (__bf16)a.z; r[3] = (__bf16)a.w;
    r[4] = (__bf16)b.x; r[5] = (__bf16)b.y; r[6] = (__bf16)b.z; r[7] = (__bf16)b.w;
    return r;
}

// C[t][n] = dot(emb[tok(t)], W[n]) + bih[n] + bhh[n]
__global__ __launch_bounds__(256) void input_gemm(
    const float* __restrict__ emb,   // [V, 1024]
    const int* __restrict__ toks,    // [256]
    const int* __restrict__ start,   // null => tok(t)=toks[t]; else shifted decoder input
    const float* __restrict__ W,     // [4096, 1024]
    const float* __restrict__ bih,   // [4096]
    const float* __restrict__ bhh,   // [4096]
    float* __restrict__ out)         // [256, 4096]
{
    __shared__ int stok[SLEN];
    int tid = threadIdx.x;
    {
        int t = tid;
        int tok;
        if (start) tok = (t == 0) ? start[0] : toks[t - 1];
        else       tok = toks[t];
        stok[t] = tok;
    }
    __syncthreads();

    int wave = tid >> 6, lane = tid & 63;
    int l15 = lane & 15, quad = lane >> 4;
    int n = (blockIdx.x * 4 + wave) * 16 + l15;
    const float* wrow = W + (size_t)n * HDIM + quad * 8;

    f32x4 acc[16] = {};
    for (int kt = 0; kt < HDIM / 32; ++kt) {
        float4 b0 = *(const float4*)(wrow + kt * 32);
        float4 b1 = *(const float4*)(wrow + kt * 32 + 4);
        bf16x8 bf = cvt8(b0, b1);
#pragma unroll
        for (int mt = 0; mt < 16; ++mt) {
            const float* arow = emb + (size_t)stok[mt * 16 + l15] * HDIM + kt * 32 + quad * 8;
            bf16x8 af = cvt8(*(const float4*)arow, *(const float4*)(arow + 4));
            acc[mt] = __builtin_amdgcn_mfma_f32_16x16x32_bf16(af, bf, acc[mt], 0, 0, 0);
        }
    }
    float bias = bih[n] + bhh[n];
#pragma unroll
    for (int mt = 0; mt < 16; ++mt)
#pragma unroll
        for (int r = 0; r < 4; ++r) {
            int t = mt * 16 + quad * 4 + r;
            out[(size_t)t * G4 + n] = acc[mt][r] + bias;
        }
}

// Persistent recurrence kernel: 512 LSTM steps, one grid barrier per step.
// 128 WGs x 256 thr. WG b owns hidden j in [b*8, b*8+8) => gate rows
// {g*1024 + j : g in 0..3}. Whh slice lives in per-thread registers:
// thread (rg = wave*2 + lane/32, ks = lane&31) holds rows lr=rg*4..rg*4+3
// (lr -> gate g=lr>>3, local jl=lr&7) over k-range [ks*32, ks*32+32).
// h is broadcast through a global double buffer with agent-scope atomics
// (cross-XCD L2s are not coherent); c never leaves registers.
__global__ __launch_bounds__(256, 1) void lstm_seq(
    const float* __restrict__ encXW,  // [256, 4096]
    const float* __restrict__ decXW,  // [256, 4096]
    const float* __restrict__ encWhh, // [4096, 1024]
    const float* __restrict__ decWhh, // [4096, 1024]
    float* __restrict__ hglob,        // [2, 1024] communication buffer
    bf16_t* __restrict__ Hs,          // [256, 1024] decoder h history (bf16)
    unsigned* __restrict__ bar)       // monotonic barrier counter (zeroed)
{
    // padded h stage: word k stored at k + (k>>5)  -> stride-32 reads are
    // bank-conflict-free (bank = (ks + i) & 31 spans all banks)
    __shared__ float sh[HDIM + HDIM / 32];
    __shared__ float sg[32];

    const int tid = threadIdx.x;
    const int wg = blockIdx.x;
    const int wave = tid >> 6, lane = tid & 63;
    const int rg = (wave << 1) | (lane >> 5);  // 0..7 row group
    const int ks = lane & 31;                  // k-chunk index
    const int j0 = wg * HPW;

    float4 w[4][8];  // 128 VGPRs of Whh, register-resident across all steps
    auto load_w = [&](const float* __restrict__ Wsrc) {
#pragma unroll
        for (int r = 0; r < 4; ++r) {
            int lr = rg * 4 + r;
            const float* src = Wsrc + (size_t)((lr >> 3) * HDIM + j0 + (lr & 7)) * HDIM + ks * 32;
#pragma unroll
            for (int i = 0; i < 8; ++i) w[r][i] = *(const float4*)(src + i * 4);
        }
    };
    load_w(encWhh);

    float creg = 0.f;  // threads 0..7: c[j0+tid], persistent across steps

    for (int t = 0; t < SLEN + TLEN; ++t) {
        if (t == SLEN) load_w(decWhh);  // enc -> dec weight swap (one-time)

        const float* xw = (t < SLEN) ? encXW + (size_t)t * G4
                                     : decXW + (size_t)(t - SLEN) * G4;
        // prefetch gates_x for the finalize threads (overlaps staging+matvec)
        float xg0 = 0.f, xg1 = 0.f, xg2 = 0.f, xg3 = 0.f;
        if (tid < HPW) {
            int j = j0 + tid;
            xg0 = xw[0 * HDIM + j];
            xg1 = xw[1 * HDIM + j];
            xg2 = xw[2 * HDIM + j];
            xg3 = xw[3 * HDIM + j];
        }

        // stage h into LDS (t=0: h0 = 0, no global read)
        if (t == 0) {
            for (int k = tid; k < HDIM; k += 256) sh[k + (k >> 5)] = 0.f;
        } else {
            const float* hin = hglob + (size_t)(t & 1) * HDIM;
            for (int k = tid; k < HDIM; k += 256) {
                float v = __hip_atomic_load(hin + k, __ATOMIC_RELAXED,
                                            __HIP_MEMORY_SCOPE_AGENT);
                sh[k + (k >> 5)] = v;
            }
        }
        __syncthreads();

        // h chunk -> registers (conflict-free b32 reads)
        float hv[32];
#pragma unroll
        for (int i = 0; i < 32; ++i) hv[i] = sh[ks * 33 + i];

        // 4 rows x 32 MACs from registers
        float s0 = 0.f, s1 = 0.f, s2 = 0.f, s3 = 0.f;
#pragma unroll
        for (int i = 0; i < 8; ++i) {
            float hx = hv[4 * i], hy = hv[4 * i + 1], hz = hv[4 * i + 2], hw = hv[4 * i + 3];
            s0 += w[0][i].x * hx + w[0][i].y * hy + w[0][i].z * hz + w[0][i].w * hw;
            s1 += w[1][i].x * hx + w[1][i].y * hy + w[1][i].z * hz + w[1][i].w * hw;
            s2 += w[2][i].x * hx + w[2][i].y * hy + w[2][i].z * hz + w[2][i].w * hw;
            s3 += w[3][i].x * hx + w[3][i].y * hy + w[3][i].z * hz + w[3][i].w * hw;
        }
        // reduce across the 32 ks-lanes (each half-wave is one rg group)
        float ss[4] = {s0, s1, s2, s3};
#pragma unroll
        for (int r = 0; r < 4; ++r) {
            float s = ss[r];
            s += __shfl_down(s, 16, 32);
            s += __shfl_down(s, 8, 32);
            s += __shfl_down(s, 4, 32);
            s += __shfl_down(s, 2, 32);
            s += __shfl_down(s, 1, 32);
            if (ks == 0) sg[rg * 4 + r] = s;
        }
        __syncthreads();

        // finalize: threads 0..7 own hidden jl = tid
        if (tid < HPW) {
            int j = j0 + tid;
            float gi = sg[0 * 8 + tid] + xg0;
            float gf = sg[1 * 8 + tid] + xg1;
            float gg = sg[2 * 8 + tid] + xg2;
            float go = sg[3 * 8 + tid] + xg3;
            float ii = 1.f / (1.f + expf(-gi));
            float ff = 1.f / (1.f + expf(-gf));
            float g  = tanhf(gg);
            float oo = 1.f / (1.f + expf(-go));
            float cn = ff * creg + ii * g;
            float hn = oo * tanhf(cn);
            creg = cn;
            if (t >= SLEN) Hs[(size_t)(t - SLEN) * HDIM + j] = (bf16_t)hn;
            // publish h at the device-coherent point (cross-XCD visible)
            __hip_atomic_store(hglob + (size_t)((t + 1) & 1) * HDIM + j, hn,
                               __ATOMIC_RELAXED, __HIP_MEMORY_SCOPE_AGENT);
            // agent-scope fence: make the h stores part of the release chain
            // that tid 0's barrier-add publishes (formal memory-model safety;
            // hardware-wise the vmcnt(0) drain before s_barrier already
            // guarantees completion at the coherent point).
            __threadfence();
        }
        __syncthreads();
        if (t != SLEN + TLEN - 1) {
            if (tid == 0) {
                unsigned target = (unsigned)(t + 1) * NWGC;
                __hip_atomic_fetch_add(bar, 1u, __ATOMIC_RELEASE,
                                       __HIP_MEMORY_SCOPE_AGENT);
                while (__hip_atomic_load(bar, __ATOMIC_RELAXED,
                                         __HIP_MEMORY_SCOPE_AGENT) < target)
                    __builtin_amdgcn_s_sleep(1);
                (void)__hip_atomic_load(bar, __ATOMIC_ACQUIRE,
                                        __HIP_MEMORY_SCOPE_AGENT);
            }
            __syncthreads();
        }
    }
}

// logits[t][n] = dot(Hs_bf16[t], lin_W[n]) + b[n]
__global__ __launch_bounds__(256) void out_gemm(
    const bf16_t* __restrict__ Hs,   // [256, 1024] bf16
    const float* __restrict__ W,     // [32000, 1024]
    const float* __restrict__ bias,  // [32000]
    float* __restrict__ out)         // [256, 32000]
{
    int tid = threadIdx.x;
    int wave = tid >> 6, lane = tid & 63;
    int l15 = lane & 15, quad = lane >> 4;
    int n = (blockIdx.x * 4 + wave) * 16 + l15;
    const float* wrow = W + (size_t)n * HDIM + quad * 8;

    f32x4 acc[16] = {};
    for (int kt = 0; kt < HDIM / 32; ++kt) {
        float4 b0 = *(const float4*)(wrow + kt * 32);
        float4 b1 = *(const float4*)(wrow + kt * 32 + 4);
        bf16x8 bf = cvt8(b0, b1);
#pragma unroll
        for (int mt = 0; mt < 16; ++mt) {
            bf16x8 af = *(const bf16x8*)(Hs + (size_t)(mt * 16 + l15) * HDIM + kt * 32 + quad * 8);
            acc[mt] = __builtin_amdgcn_mfma_f32_16x16x32_bf16(af, bf, acc[mt], 0, 0, 0);
        }
    }
    float bv = bias[n];
#pragma unroll
    for (int mt = 0; mt < 16; ++mt)
#pragma unroll
        for (int r = 0; r < 4; ++r) {
            int t = mt * 16 + quad * 4 + r;
            out[(size_t)t * VOUTN + n] = acc[mt][r] + bv;
        }
}

// in-place log_softmax per row; 256 blocks (one per t) x 256 thr
__global__ __launch_bounds__(256) void log_softmax_k(float* __restrict__ out)
{
    float* row = out + (size_t)blockIdx.x * VOUTN;
    int tid = threadIdx.x;
    int wave = tid >> 6, lane = tid & 63;
    __shared__ float sm[4], ss[4];

    float m = -1e30f;
    for (int i = tid; i < VOUTN; i += 256) m = fmaxf(m, row[i]);
    for (int o = 32; o; o >>= 1) m = fmaxf(m, __shfl_down(m, o, 64));
    if (lane == 0) sm[wave] = m;
    __syncthreads();
    float bm = fmaxf(fmaxf(sm[0], sm[1]), fmaxf(sm[2], sm[3]));

    float s = 0.f;
    for (int i = tid; i < VOUTN; i += 256) s += expf(row[i] - bm);
    for (int o = 32; o; o >>= 1) s += __shfl_down(s, o, 64);
    if (lane == 0) ss[wave] = s;
    __syncthreads();
    float lse = bm + logf(ss[0] + ss[1] + ss[2] + ss[3]);

    for (int i = tid; i < VOUTN; i += 256) row[i] -= lse;
}

extern "C" void kernel_launch(void* const* d_in, const int* in_sizes, int n_in,
                              void* d_out, int out_size, void* d_ws, size_t ws_size,
                              hipStream_t stream) {
    const int*   src     = (const int*)d_in[0];
    const int*   trg     = (const int*)d_in[1];
    const int*   start   = (const int*)d_in[2];
    const float* enc_emb = (const float*)d_in[3];
    const float* enc_Wih = (const float*)d_in[4];
    const float* enc_Whh = (const float*)d_in[5];
    const float* enc_bih = (const float*)d_in[6];
    const float* enc_bhh = (const float*)d_in[7];
    const float* dec_emb = (const float*)d_in[8];
    const float* dec_Wih = (const float*)d_in[9];
    const float* dec_Whh = (const float*)d_in[10];
    const float* dec_bih = (const float*)d_in[11];
    const float* dec_bhh = (const float*)d_in[12];
    const float* lin_W   = (const float*)d_in[13];
    const float* lin_b   = (const float*)d_in[14];
    float* out = (float*)d_out;

    char* ws = (char*)d_ws;
    float*    encXW = (float*)(ws);                 // 256*4096 f32 = 4 MiB
    float*    decXW = (float*)(ws + 4194304);       // 4 MiB
    bf16_t*   Hs    = (bf16_t*)(ws + 8388608);      // 256*1024 bf16 = 512 KiB
    float*    hglob = (float*)(ws + 8912896);       // 2*1024 f32 = 8 KiB
    unsigned* bar   = (unsigned*)(ws + 8921088);    // barrier counter

    // barrier counter must start at 0 (ws is poisoned 0xAA before launch);
    // h0/c0 need no init: step 0 uses local zeros, c lives in registers.
    hipMemsetAsync(bar, 0, 64, stream);

    // precompute x@Wih^T + biases for all timesteps (parallel across t)
    input_gemm<<<64, 256, 0, stream>>>(enc_emb, src, nullptr, enc_Wih, enc_bih, enc_bhh, encXW);
    input_gemm<<<64, 256, 0, stream>>>(dec_emb, trg, start,   dec_Wih, dec_bih, dec_bhh, decXW);

    // persistent recurrence: 128 small WGs (<< 256 CUs, trivially co-resident),
    // all 512 steps inside one kernel with a device-scope atomic grid barrier.
    lstm_seq<<<NWGC, 256, 0, stream>>>(encXW, decXW, enc_Whh, dec_Whh, hglob, Hs, bar);

    // output projection + log_softmax
    out_gemm<<<500, 256, 0, stream>>>(Hs, lin_W, lin_b, out);
    log_softmax_k<<<256, 256, 0, stream>>>(out);
}

// Round 3
// 2522.165 us; speedup vs baseline: 2.2302x; 2.2302x over previous
//
#include <hip/hip_runtime.h>
#include <hip/hip_bf16.h>

// Seq2Seq (batch=1): enc LSTM (S=256) -> dec LSTM (T=256, teacher forcing)
// -> linear (VOUT=32000) -> log_softmax.
//
// v4: v3's central atomic-counter grid barrier measured ~9 us/step (4565 us
// total, VALUBusy 2.2%) -- slower than per-step launches. Replace it with
// TAGGED-DATA dataflow sync: h element j for step t is published as
// u64 = ((t)<<32 | f32bits) into a fresh per-step buffer hseq[t][j].
// Consumers poll the tags of the words they need; no barrier, no RMW
// contention, max skew is structurally one step. Whh stays register/AGPR
// resident (verified: FETCH 42MB = one weight read).
//
//   1) input_gemm: gates_x[t][r] = dot(emb[tok(t)], Wih[r]) + bih[r] + bhh[r]
//   2) lstm_seq: persistent, 512 steps, tagged-h dataflow sync
//   3) out_gemm: logits = Hs @ lin_W^T + b (MFMA bf16)
//   4) log_softmax per row

#define HDIM 1024
#define SLEN 256
#define TLEN 256
#define VOUTN 32000
#define G4 4096
#define NWGC 128      // workgroups in persistent kernel (co-resident on 256 CUs)
#define HPW 8         // hidden indices per WG = 1024/128

typedef __bf16 bf16_t;
typedef __bf16 bf16x8 __attribute__((ext_vector_type(8)));
typedef float f32x4 __attribute__((ext_vector_type(4)));
typedef unsigned long long u64;

static __device__ inline bf16x8 cvt8(float4 a, float4 b) {
    bf16x8 r;
    r[0] = (__bf16)a.x; r[1] = (__bf16)a.y; r[2] = (__bf16)a.z; r[3] = (__bf16)a.w;
    r[4] = (__bf16)b.x; r[5] = (__bf16)b.y; r[6] = (__bf16)b.z; r[7] = (__bf16)b.w;
    return r;
}

// C[t][n] = dot(emb[tok(t)], W[n]) + bih[n] + bhh[n]
__global__ __launch_bounds__(256) void input_gemm(
    const float* __restrict__ emb,   // [V, 1024]
    const int* __restrict__ toks,    // [256]
    const int* __restrict__ start,   // null => tok(t)=toks[t]; else shifted decoder input
    const float* __restrict__ W,     // [4096, 1024]
    const float* __restrict__ bih,   // [4096]
    const float* __restrict__ bhh,   // [4096]
    float* __restrict__ out)         // [256, 4096]
{
    __shared__ int stok[SLEN];
    int tid = threadIdx.x;
    {
        int t = tid;
        int tok;
        if (start) tok = (t == 0) ? start[0] : toks[t - 1];
        else       tok = toks[t];
        stok[t] = tok;
    }
    __syncthreads();

    int wave = tid >> 6, lane = tid & 63;
    int l15 = lane & 15, quad = lane >> 4;
    int n = (blockIdx.x * 4 + wave) * 16 + l15;
    const float* wrow = W + (size_t)n * HDIM + quad * 8;

    f32x4 acc[16] = {};
    for (int kt = 0; kt < HDIM / 32; ++kt) {
        float4 b0 = *(const float4*)(wrow + kt * 32);
        float4 b1 = *(const float4*)(wrow + kt * 32 + 4);
        bf16x8 bf = cvt8(b0, b1);
#pragma unroll
        for (int mt = 0; mt < 16; ++mt) {
            const float* arow = emb + (size_t)stok[mt * 16 + l15] * HDIM + kt * 32 + quad * 8;
            bf16x8 af = cvt8(*(const float4*)arow, *(const float4*)(arow + 4));
            acc[mt] = __builtin_amdgcn_mfma_f32_16x16x32_bf16(af, bf, acc[mt], 0, 0, 0);
        }
    }
    float bias = bih[n] + bhh[n];
#pragma unroll
    for (int mt = 0; mt < 16; ++mt)
#pragma unroll
        for (int r = 0; r < 4; ++r) {
            int t = mt * 16 + quad * 4 + r;
            out[(size_t)t * G4 + n] = acc[mt][r] + bias;
        }
}

// Persistent recurrence kernel: 512 LSTM steps, tagged-h dataflow sync.
// 128 WGs x 256 thr. WG b owns hidden j in [b*8, b*8+8) => gate rows
// {g*1024 + j : g in 0..3}. Whh slice lives in per-thread registers/AGPRs:
// thread (rg = wave*2 + lane/32, ks = lane&31) holds rows lr=rg*4..rg*4+3
// over k-range [ks*32, ks*32+32).
// h input for step t lives in hseq[t][0..1023] as (tag=t)<<32 | f32bits;
// buffer is fresh per step -> no WAR hazard, no barrier needed.
__global__ __launch_bounds__(256, 1) void lstm_seq(
    const float* __restrict__ encXW,  // [256, 4096]
    const float* __restrict__ decXW,  // [256, 4096]
    const float* __restrict__ encWhh, // [4096, 1024]
    const float* __restrict__ decWhh, // [4096, 1024]
    u64* __restrict__ hseq,           // [512, 1024] tagged h (zeroed; tag 0 invalid)
    bf16_t* __restrict__ Hs)          // [256, 1024] decoder h history (bf16)
{
    // padded h stage: word k stored at k + (k>>5) -> stride-32 reads are
    // bank-conflict-free
    __shared__ float sh[HDIM + HDIM / 32];
    __shared__ float sg[32];

    const int tid = threadIdx.x;
    const int wg = blockIdx.x;
    const int wave = tid >> 6, lane = tid & 63;
    const int rg = (wave << 1) | (lane >> 5);  // 0..7 row group
    const int ks = lane & 31;                  // k-chunk index
    const int j0 = wg * HPW;

    float4 w[4][8];  // 128 f32 of Whh, register/AGPR-resident across all steps
    auto load_w = [&](const float* __restrict__ Wsrc) {
#pragma unroll
        for (int r = 0; r < 4; ++r) {
            int lr = rg * 4 + r;
            const float* src = Wsrc + (size_t)((lr >> 3) * HDIM + j0 + (lr & 7)) * HDIM + ks * 32;
#pragma unroll
            for (int i = 0; i < 8; ++i) w[r][i] = *(const float4*)(src + i * 4);
        }
    };
    load_w(encWhh);

    float creg = 0.f;  // threads 0..7: c[j0+tid], persistent across steps

    for (int t = 0; t < SLEN + TLEN; ++t) {
        if (t == SLEN) load_w(decWhh);  // enc -> dec weight swap (one-time)

        const float* xw = (t < SLEN) ? encXW + (size_t)t * G4
                                     : decXW + (size_t)(t - SLEN) * G4;
        // prefetch gates_x for the finalize threads
        float xg0 = 0.f, xg1 = 0.f, xg2 = 0.f, xg3 = 0.f;
        if (tid < HPW) {
            int j = j0 + tid;
            xg0 = xw[0 * HDIM + j];
            xg1 = xw[1 * HDIM + j];
            xg2 = xw[2 * HDIM + j];
            xg3 = xw[3 * HDIM + j];
        }

        // stage h into LDS. Each thread owns words k = tid*4 .. tid*4+3
        // (32 B contiguous, 1-2 cache lines). t=0: h0 = 0, no global read.
        const int k = tid << 2;
        const int pad = k >> 5;        // (k+i)>>5 == k>>5 for i<4 (k is 4-aligned)
        if (t == 0) {
            sh[k + pad]     = 0.f;
            sh[k + pad + 1] = 0.f;
            sh[k + pad + 2] = 0.f;
            sh[k + pad + 3] = 0.f;
        } else {
            const u64* hin = hseq + (size_t)t * HDIM + k;
            const unsigned tag = (unsigned)t;
            u64 v0, v1, v2, v3;
            for (;;) {
                // issue all 4 loads back-to-back (fast path: one vmcnt wait)
                v0 = __hip_atomic_load(hin + 0, __ATOMIC_RELAXED, __HIP_MEMORY_SCOPE_AGENT);
                v1 = __hip_atomic_load(hin + 1, __ATOMIC_RELAXED, __HIP_MEMORY_SCOPE_AGENT);
                v2 = __hip_atomic_load(hin + 2, __ATOMIC_RELAXED, __HIP_MEMORY_SCOPE_AGENT);
                v3 = __hip_atomic_load(hin + 3, __ATOMIC_RELAXED, __HIP_MEMORY_SCOPE_AGENT);
                if ((unsigned)(v0 >> 32) == tag && (unsigned)(v1 >> 32) == tag &&
                    (unsigned)(v2 >> 32) == tag && (unsigned)(v3 >> 32) == tag) break;
                __builtin_amdgcn_s_sleep(1);
            }
            sh[k + pad]     = __uint_as_float((unsigned)v0);
            sh[k + pad + 1] = __uint_as_float((unsigned)v1);
            sh[k + pad + 2] = __uint_as_float((unsigned)v2);
            sh[k + pad + 3] = __uint_as_float((unsigned)v3);
        }
        __syncthreads();

        // h chunk -> registers (conflict-free b32 reads)
        float hv[32];
#pragma unroll
        for (int i = 0; i < 32; ++i) hv[i] = sh[ks * 33 + i];

        // 4 rows x 32 MACs from registers
        float s0 = 0.f, s1 = 0.f, s2 = 0.f, s3 = 0.f;
#pragma unroll
        for (int i = 0; i < 8; ++i) {
            float hx = hv[4 * i], hy = hv[4 * i + 1], hz = hv[4 * i + 2], hw = hv[4 * i + 3];
            s0 += w[0][i].x * hx + w[0][i].y * hy + w[0][i].z * hz + w[0][i].w * hw;
            s1 += w[1][i].x * hx + w[1][i].y * hy + w[1][i].z * hz + w[1][i].w * hw;
            s2 += w[2][i].x * hx + w[2][i].y * hy + w[2][i].z * hz + w[2][i].w * hw;
            s3 += w[3][i].x * hx + w[3][i].y * hy + w[3][i].z * hz + w[3][i].w * hw;
        }
        // reduce across the 32 ks-lanes (each half-wave is one rg group)
        float ss[4] = {s0, s1, s2, s3};
#pragma unroll
        for (int r = 0; r < 4; ++r) {
            float s = ss[r];
            s += __shfl_down(s, 16, 32);
            s += __shfl_down(s, 8, 32);
            s += __shfl_down(s, 4, 32);
            s += __shfl_down(s, 2, 32);
            s += __shfl_down(s, 1, 32);
            if (ks == 0) sg[rg * 4 + r] = s;
        }
        __syncthreads();
        // after this sync every thread has consumed sh; next iteration's
        // stage may overwrite it, and sg writes of step t+1 happen only
        // after all threads (incl. finalizers) pass the NEXT stage sync.

        // finalize: threads 0..7 own hidden jl = tid
        if (tid < HPW) {
            int j = j0 + tid;
            float gi = sg[0 * 8 + tid] + xg0;
            float gf = sg[1 * 8 + tid] + xg1;
            float gg = sg[2 * 8 + tid] + xg2;
            float go = sg[3 * 8 + tid] + xg3;
            float ii = 1.f / (1.f + expf(-gi));
            float ff = 1.f / (1.f + expf(-gf));
            float g  = tanhf(gg);
            float oo = 1.f / (1.f + expf(-go));
            float cn = ff * creg + ii * g;
            float hn = oo * tanhf(cn);
            creg = cn;
            if (t >= SLEN) Hs[(size_t)(t - SLEN) * HDIM + j] = (bf16_t)hn;
            if (t < SLEN + TLEN - 1) {
                // publish tagged h for step t+1: data and flag in one u64,
                // so relaxed agent-scope store is sufficient.
                u64 pk = ((u64)(unsigned)(t + 1) << 32) | (u64)__float_as_uint(hn);
                __hip_atomic_store(hseq + (size_t)(t + 1) * HDIM + j, pk,
                                   __ATOMIC_RELAXED, __HIP_MEMORY_SCOPE_AGENT);
            }
        }
        // no grid barrier: consumers gate on the tags themselves.
    }
}

// logits[t][n] = dot(Hs_bf16[t], lin_W[n]) + b[n]
__global__ __launch_bounds__(256) void out_gemm(
    const bf16_t* __restrict__ Hs,   // [256, 1024] bf16
    const float* __restrict__ W,     // [32000, 1024]
    const float* __restrict__ bias,  // [32000]
    float* __restrict__ out)         // [256, 32000]
{
    int tid = threadIdx.x;
    int wave = tid >> 6, lane = tid & 63;
    int l15 = lane & 15, quad = lane >> 4;
    int n = (blockIdx.x * 4 + wave) * 16 + l15;
    const float* wrow = W + (size_t)n * HDIM + quad * 8;

    f32x4 acc[16] = {};
    for (int kt = 0; kt < HDIM / 32; ++kt) {
        float4 b0 = *(const float4*)(wrow + kt * 32);
        float4 b1 = *(const float4*)(wrow + kt * 32 + 4);
        bf16x8 bf = cvt8(b0, b1);
#pragma unroll
        for (int mt = 0; mt < 16; ++mt) {
            bf16x8 af = *(const bf16x8*)(Hs + (size_t)(mt * 16 + l15) * HDIM + kt * 32 + quad * 8);
            acc[mt] = __builtin_amdgcn_mfma_f32_16x16x32_bf16(af, bf, acc[mt], 0, 0, 0);
        }
    }
    float bv = bias[n];
#pragma unroll
    for (int mt = 0; mt < 16; ++mt)
#pragma unroll
        for (int r = 0; r < 4; ++r) {
            int t = mt * 16 + quad * 4 + r;
            out[(size_t)t * VOUTN + n] = acc[mt][r] + bv;
        }
}

// in-place log_softmax per row; 256 blocks (one per t) x 256 thr
__global__ __launch_bounds__(256) void log_softmax_k(float* __restrict__ out)
{
    float* row = out + (size_t)blockIdx.x * VOUTN;
    int tid = threadIdx.x;
    int wave = tid >> 6, lane = tid & 63;
    __shared__ float sm[4], ss[4];

    float m = -1e30f;
    for (int i = tid; i < VOUTN; i += 256) m = fmaxf(m, row[i]);
    for (int o = 32; o; o >>= 1) m = fmaxf(m, __shfl_down(m, o, 64));
    if (lane == 0) sm[wave] = m;
    __syncthreads();
    float bm = fmaxf(fmaxf(sm[0], sm[1]), fmaxf(sm[2], sm[3]));

    float s = 0.f;
    for (int i = tid; i < VOUTN; i += 256) s += expf(row[i] - bm);
    for (int o = 32; o; o >>= 1) s += __shfl_down(s, o, 64);
    if (lane == 0) ss[wave] = s;
    __syncthreads();
    float lse = bm + logf(ss[0] + ss[1] + ss[2] + ss[3]);

    for (int i = tid; i < VOUTN; i += 256) row[i] -= lse;
}

extern "C" void kernel_launch(void* const* d_in, const int* in_sizes, int n_in,
                              void* d_out, int out_size, void* d_ws, size_t ws_size,
                              hipStream_t stream) {
    const int*   src     = (const int*)d_in[0];
    const int*   trg     = (const int*)d_in[1];
    const int*   start   = (const int*)d_in[2];
    const float* enc_emb = (const float*)d_in[3];
    const float* enc_Wih = (const float*)d_in[4];
    const float* enc_Whh = (const float*)d_in[5];
    const float* enc_bih = (const float*)d_in[6];
    const float* enc_bhh = (const float*)d_in[7];
    const float* dec_emb = (const float*)d_in[8];
    const float* dec_Wih = (const float*)d_in[9];
    const float* dec_Whh = (const float*)d_in[10];
    const float* dec_bih = (const float*)d_in[11];
    const float* dec_bhh = (const float*)d_in[12];
    const float* lin_W   = (const float*)d_in[13];
    const float* lin_b   = (const float*)d_in[14];
    float* out = (float*)d_out;

    char* ws = (char*)d_ws;
    float*  encXW = (float*)(ws);                   // 256*4096 f32 = 4 MiB
    float*  decXW = (float*)(ws + 4194304);         // 4 MiB
    bf16_t* Hs    = (bf16_t*)(ws + 8388608);        // 256*1024 bf16 = 512 KiB
    u64*    hseq  = (u64*)(ws + 9437184);           // [512][1024] u64 = 4 MiB

    // zero the tagged-h buffer (tag 0 is invalid; makes correctness
    // independent of workspace poison semantics). Stream-ordered, ~1 us.
    hipMemsetAsync(hseq, 0, (size_t)(SLEN + TLEN) * HDIM * sizeof(u64), stream);

    // precompute x@Wih^T + biases for all timesteps (parallel across t)
    input_gemm<<<64, 256, 0, stream>>>(enc_emb, src, nullptr, enc_Wih, enc_bih, enc_bhh, encXW);
    input_gemm<<<64, 256, 0, stream>>>(dec_emb, trg, start,   dec_Wih, dec_bih, dec_bhh, decXW);

    // persistent recurrence: 128 co-resident WGs, 512 steps, dataflow sync
    lstm_seq<<<NWGC, 256, 0, stream>>>(encXW, decXW, enc_Whh, dec_Whh, hseq, Hs);

    // output projection + log_softmax
    out_gemm<<<500, 256, 0, stream>>>(Hs, lin_W, lin_b, out);
    log_softmax_k<<<256, 256, 0, stream>>>(out);
}

// Round 4
// 2297.308 us; speedup vs baseline: 2.4485x; 1.0979x over previous
//
#include <hip/hip_runtime.h>
#include <hip/hip_bf16.h>

// Seq2Seq (batch=1): enc LSTM (S=256) -> dec LSTM (T=256, teacher forcing)
// -> linear (VOUT=32000) -> log_softmax.
//
// v5: v4 measured 2522 us (lstm_seq 1458, VALUBusy 6.5% -> latency-bound on
// h handoff). Changes:
//  - lstm_seq poll: wave-0-only, representative-word phase-1 (1 tag per
//    64B producer line, tight loop) + full verify phase-2. 6x less poll
//    traffic, shorter detect period.
//  - fast __expf-based activations in the serial finalize chain.
//  - xw_all: enc+dec input GEMM in ONE kernel (512 blocks x 64 thr), also
//    zeroes hseq -> hipMemsetAsync dropped. 6 -> 4 dispatches.
//  - log_softmax: 1024 thr/block, float4, __expf/__logf.

#define HDIM 1024
#define SLEN 256
#define TLEN 256
#define VOUTN 32000
#define G4 4096
#define NWGC 128      // workgroups in persistent kernel (co-resident on 256 CUs)
#define HPW 8         // hidden indices per WG = 1024/128

typedef __bf16 bf16_t;
typedef __bf16 bf16x8 __attribute__((ext_vector_type(8)));
typedef float f32x4 __attribute__((ext_vector_type(4)));
typedef unsigned long long u64;

static __device__ inline bf16x8 cvt8(float4 a, float4 b) {
    bf16x8 r;
    r[0] = (__bf16)a.x; r[1] = (__bf16)a.y; r[2] = (__bf16)a.z; r[3] = (__bf16)a.w;
    r[4] = (__bf16)b.x; r[5] = (__bf16)b.y; r[6] = (__bf16)b.z; r[7] = (__bf16)b.w;
    return r;
}

static __device__ inline float sig_f(float x) {
    return 1.f / (1.f + __expf(-x));          // __expf(-x)->inf for x<<0 => 0: graceful
}
static __device__ inline float tanh_f(float x) {
    float e = __expf(-2.f * fabsf(x));        // in (0,1], no overflow
    float r = (1.f - e) / (1.f + e);
    return copysignf(r, x);
}

// enc+dec input GEMM: out[t][n] = dot(emb[tok(t)], W[n]) + bih[n] + bhh[n]
// 512 blocks x 64 thr (1 wave = one 16-wide n-tile, loops 16 m-tiles).
// blocks 0..255 = encoder, 256..511 = decoder. Also zeroes hseq (so no
// hipMemsetAsync is needed; tag 0 is invalid).
__global__ __launch_bounds__(64) void xw_all(
    const int* __restrict__ src, const int* __restrict__ trg,
    const int* __restrict__ start,
    const float* __restrict__ enc_emb, const float* __restrict__ enc_Wih,
    const float* __restrict__ enc_bih, const float* __restrict__ enc_bhh,
    const float* __restrict__ dec_emb, const float* __restrict__ dec_Wih,
    const float* __restrict__ dec_bih, const float* __restrict__ dec_bhh,
    float* __restrict__ encXW, float* __restrict__ decXW,
    u64* __restrict__ hseq)          // [512,1024] -> zeroed here
{
    const int b = blockIdx.x, tid = threadIdx.x;

    // cooperative zero of hseq (512*1024 u64 over 512*64 threads: 16 each)
    for (size_t i = (size_t)b * 64 + tid; i < (size_t)512 * 1024; i += (size_t)512 * 64)
        hseq[i] = 0ULL;

    const bool enc = (b < 256);
    const int*   toks = enc ? src : trg;
    const float* emb  = enc ? enc_emb : dec_emb;
    const float* W    = enc ? enc_Wih : dec_Wih;
    const float* bi   = enc ? enc_bih : dec_bih;
    const float* bh   = enc ? enc_bhh : dec_bhh;
    float*       outp = enc ? encXW : decXW;

    __shared__ int stok[SLEN];
    for (int i = tid; i < SLEN; i += 64)
        stok[i] = enc ? toks[i] : (i == 0 ? start[0] : toks[i - 1]);
    __syncthreads();

    const int l15 = tid & 15, quad = tid >> 4;
    const int n = (b & 255) * 16 + l15;
    const float* wrow = W + (size_t)n * HDIM + quad * 8;

    f32x4 acc[16] = {};
    for (int kt = 0; kt < HDIM / 32; ++kt) {
        float4 b0 = *(const float4*)(wrow + kt * 32);
        float4 b1 = *(const float4*)(wrow + kt * 32 + 4);
        bf16x8 bf = cvt8(b0, b1);
#pragma unroll
        for (int mt = 0; mt < 16; ++mt) {
            const float* ar = emb + (size_t)stok[mt * 16 + l15] * HDIM + kt * 32 + quad * 8;
            bf16x8 af = cvt8(*(const float4*)ar, *(const float4*)(ar + 4));
            acc[mt] = __builtin_amdgcn_mfma_f32_16x16x32_bf16(af, bf, acc[mt], 0, 0, 0);
        }
    }
    float bias = bi[n] + bh[n];
#pragma unroll
    for (int mt = 0; mt < 16; ++mt)
#pragma unroll
        for (int r = 0; r < 4; ++r) {
            int t = mt * 16 + quad * 4 + r;
            outp[(size_t)t * G4 + n] = acc[mt][r] + bias;
        }
}

// Persistent recurrence: 512 LSTM steps, tagged-h dataflow sync.
// 128 WGs x 256 thr. WG b owns hidden j in [b*8, b*8+8); Whh slice in
// registers/AGPRs. h for step t lives in hseq[t][j] as ((u64)t<<32)|f32bits;
// each producer WG's 8 words form exactly one 64-B line -> wave 0 polls one
// representative word per line (phase 1), then loads+verifies all (phase 2).
__global__ __launch_bounds__(256, 1) void lstm_seq(
    const float* __restrict__ encXW,  // [256, 4096]
    const float* __restrict__ decXW,  // [256, 4096]
    const float* __restrict__ encWhh, // [4096, 1024]
    const float* __restrict__ decWhh, // [4096, 1024]
    u64* __restrict__ hseq,           // [512, 1024] tagged h (zeroed by xw_all)
    bf16_t* __restrict__ Hs)          // [256, 1024] decoder h history (bf16)
{
    // padded h stage: word j stored at j + (j>>5) -> stride-32 reads conflict-free
    __shared__ float sh[HDIM + HDIM / 32];
    __shared__ float sg[32];

    const int tid = threadIdx.x;
    const int wg = blockIdx.x;
    const int wave = tid >> 6, lane = tid & 63;
    const int rg = (wave << 1) | (lane >> 5);  // 0..7 row group
    const int ks = lane & 31;                  // k-chunk index
    const int j0 = wg * HPW;

    float4 w[4][8];  // 128 f32 of Whh, register/AGPR-resident across all steps
    auto load_w = [&](const float* __restrict__ Wsrc) {
#pragma unroll
        for (int r = 0; r < 4; ++r) {
            int lr = rg * 4 + r;
            const float* srcp = Wsrc + (size_t)((lr >> 3) * HDIM + j0 + (lr & 7)) * HDIM + ks * 32;
#pragma unroll
            for (int i = 0; i < 8; ++i) w[r][i] = *(const float4*)(srcp + i * 4);
        }
    };
    load_w(encWhh);

    float creg = 0.f;  // threads 0..7: c[j0+tid], persistent across steps

    for (int t = 0; t < SLEN + TLEN; ++t) {
        if (t == SLEN) load_w(decWhh);  // enc -> dec weight swap (one-time)

        // ---- stage h into LDS: wave 0 only; waves 1-3 sleep at the barrier ----
        if (wave == 0) {
            if (t == 0) {
#pragma unroll
                for (int i = 0; i < 8; ++i) {
                    int j = lane * 8 + i;        sh[j + (j >> 5)] = 0.f;
                    int j2 = 512 + lane * 8 + i; sh[j2 + (j2 >> 5)] = 0.f;
                }
            } else {
                const u64* row = hseq + (size_t)t * HDIM;
                const unsigned tag = (unsigned)t;
                const u64* pa = row + lane * 8;        // producer line `lane`
                const u64* pb = row + 512 + lane * 8;  // producer line `64+lane`
                // phase 1: one representative word per 64-B producer line
                for (;;) {
                    u64 a0 = __hip_atomic_load(pa, __ATOMIC_RELAXED, __HIP_MEMORY_SCOPE_AGENT);
                    u64 b0 = __hip_atomic_load(pb, __ATOMIC_RELAXED, __HIP_MEMORY_SCOPE_AGENT);
                    if (__all(((unsigned)(a0 >> 32) == tag) && ((unsigned)(b0 >> 32) == tag)))
                        break;
                }
                // phase 2: full lines, verify EVERY word's tag (airtight)
                u64 av[8], bv[8];
                for (;;) {
#pragma unroll
                    for (int i = 0; i < 8; ++i)
                        av[i] = __hip_atomic_load(pa + i, __ATOMIC_RELAXED, __HIP_MEMORY_SCOPE_AGENT);
#pragma unroll
                    for (int i = 0; i < 8; ++i)
                        bv[i] = __hip_atomic_load(pb + i, __ATOMIC_RELAXED, __HIP_MEMORY_SCOPE_AGENT);
                    bool ok = true;
#pragma unroll
                    for (int i = 0; i < 8; ++i)
                        ok = ok && ((unsigned)(av[i] >> 32) == tag)
                                && ((unsigned)(bv[i] >> 32) == tag);
                    if (__all(ok)) break;
                    __builtin_amdgcn_s_sleep(1);
                }
#pragma unroll
                for (int i = 0; i < 8; ++i) {
                    int j = lane * 8 + i;
                    sh[j + (j >> 5)] = __uint_as_float((unsigned)av[i]);
                    int j2 = 512 + lane * 8 + i;
                    sh[j2 + (j2 >> 5)] = __uint_as_float((unsigned)bv[i]);
                }
            }
        }
        __syncthreads();

        // gates_x prefetch for finalize threads (regular loads: written by the
        // PREVIOUS kernel -> coherent across the dispatch boundary; issued here
        // so the latency hides under matvec+reduce)
        float xg0 = 0.f, xg1 = 0.f, xg2 = 0.f, xg3 = 0.f;
        if (tid < HPW) {
            const float* xw = (t < SLEN) ? encXW + (size_t)t * G4
                                         : decXW + (size_t)(t - SLEN) * G4;
            int j = j0 + tid;
            xg0 = xw[0 * HDIM + j];
            xg1 = xw[1 * HDIM + j];
            xg2 = xw[2 * HDIM + j];
            xg3 = xw[3 * HDIM + j];
        }

        // h chunk -> registers (conflict-free b32 reads)
        float hv[32];
#pragma unroll
        for (int i = 0; i < 32; ++i) hv[i] = sh[ks * 33 + i];

        // 4 rows x 32 MACs from registers
        float s0 = 0.f, s1 = 0.f, s2 = 0.f, s3 = 0.f;
#pragma unroll
        for (int i = 0; i < 8; ++i) {
            float hx = hv[4 * i], hy = hv[4 * i + 1], hz = hv[4 * i + 2], hw = hv[4 * i + 3];
            s0 += w[0][i].x * hx + w[0][i].y * hy + w[0][i].z * hz + w[0][i].w * hw;
            s1 += w[1][i].x * hx + w[1][i].y * hy + w[1][i].z * hz + w[1][i].w * hw;
            s2 += w[2][i].x * hx + w[2][i].y * hy + w[2][i].z * hz + w[2][i].w * hw;
            s3 += w[3][i].x * hx + w[3][i].y * hy + w[3][i].z * hz + w[3][i].w * hw;
        }
        // reduce across the 32 ks-lanes (each half-wave is one rg group)
        float ss[4] = {s0, s1, s2, s3};
#pragma unroll
        for (int r = 0; r < 4; ++r) {
            float s = ss[r];
            s += __shfl_down(s, 16, 32);
            s += __shfl_down(s, 8, 32);
            s += __shfl_down(s, 4, 32);
            s += __shfl_down(s, 2, 32);
            s += __shfl_down(s, 1, 32);
            if (ks == 0) sg[rg * 4 + r] = s;
        }
        __syncthreads();

        // finalize: threads 0..7 own hidden jl = tid
        if (tid < HPW) {
            int j = j0 + tid;
            float gi = sg[0 * 8 + tid] + xg0;
            float gf = sg[1 * 8 + tid] + xg1;
            float gg = sg[2 * 8 + tid] + xg2;
            float go = sg[3 * 8 + tid] + xg3;
            float ii = sig_f(gi);
            float ff = sig_f(gf);
            float g  = tanh_f(gg);
            float oo = sig_f(go);
            float cn = ff * creg + ii * g;
            float hn = oo * tanh_f(cn);
            creg = cn;
            if (t >= SLEN) Hs[(size_t)(t - SLEN) * HDIM + j] = (bf16_t)hn;
            if (t < SLEN + TLEN - 1) {
                // tagged publish: data+flag in one u64; the 8 lanes' stores
                // form one 64-B line -> single coalesced store transaction
                u64 pk = ((u64)(unsigned)(t + 1) << 32) | (u64)__float_as_uint(hn);
                __hip_atomic_store(hseq + (size_t)(t + 1) * HDIM + j, pk,
                                   __ATOMIC_RELAXED, __HIP_MEMORY_SCOPE_AGENT);
            }
        }
        // no grid barrier: consumers gate on the tags themselves
    }
}

// logits[t][n] = dot(Hs_bf16[t], lin_W[n]) + b[n]
__global__ __launch_bounds__(256) void out_gemm(
    const bf16_t* __restrict__ Hs,   // [256, 1024] bf16
    const float* __restrict__ W,     // [32000, 1024]
    const float* __restrict__ bias,  // [32000]
    float* __restrict__ out)         // [256, 32000]
{
    int tid = threadIdx.x;
    int wave = tid >> 6, lane = tid & 63;
    int l15 = lane & 15, quad = lane >> 4;
    int n = (blockIdx.x * 4 + wave) * 16 + l15;
    const float* wrow = W + (size_t)n * HDIM + quad * 8;

    f32x4 acc[16] = {};
    for (int kt = 0; kt < HDIM / 32; ++kt) {
        float4 b0 = *(const float4*)(wrow + kt * 32);
        float4 b1 = *(const float4*)(wrow + kt * 32 + 4);
        bf16x8 bf = cvt8(b0, b1);
#pragma unroll
        for (int mt = 0; mt < 16; ++mt) {
            bf16x8 af = *(const bf16x8*)(Hs + (size_t)(mt * 16 + l15) * HDIM + kt * 32 + quad * 8);
            acc[mt] = __builtin_amdgcn_mfma_f32_16x16x32_bf16(af, bf, acc[mt], 0, 0, 0);
        }
    }
    float bv = bias[n];
#pragma unroll
    for (int mt = 0; mt < 16; ++mt)
#pragma unroll
        for (int r = 0; r < 4; ++r) {
            int t = mt * 16 + quad * 4 + r;
            out[(size_t)t * VOUTN + n] = acc[mt][r] + bv;
        }
}

// in-place log_softmax per row; 256 blocks (one per t) x 1024 thr, float4
__global__ __launch_bounds__(1024) void log_softmax_k(float* __restrict__ out)
{
    float* row = out + (size_t)blockIdx.x * VOUTN;
    float4* r4 = (float4*)row;
    const int tid = threadIdx.x;
    const int wave = tid >> 6, lane = tid & 63;
    __shared__ float sred[16];

    float m = -1e30f;
    for (int i = tid; i < VOUTN / 4; i += 1024) {
        float4 v = r4[i];
        m = fmaxf(fmaxf(fmaxf(m, v.x), fmaxf(v.y, v.z)), v.w);
    }
    for (int o = 32; o; o >>= 1) m = fmaxf(m, __shfl_down(m, o, 64));
    if (lane == 0) sred[wave] = m;
    __syncthreads();
    float bm = sred[0];
#pragma unroll
    for (int i = 1; i < 16; ++i) bm = fmaxf(bm, sred[i]);
    __syncthreads();

    float s = 0.f;
    for (int i = tid; i < VOUTN / 4; i += 1024) {
        float4 v = r4[i];
        s += __expf(v.x - bm) + __expf(v.y - bm) + __expf(v.z - bm) + __expf(v.w - bm);
    }
    for (int o = 32; o; o >>= 1) s += __shfl_down(s, o, 64);
    if (lane == 0) sred[wave] = s;
    __syncthreads();
    float S = 0.f;
#pragma unroll
    for (int i = 0; i < 16; ++i) S += sred[i];
    float lse = bm + __logf(S);

    for (int i = tid; i < VOUTN / 4; i += 1024) {
        float4 v = r4[i];
        v.x -= lse; v.y -= lse; v.z -= lse; v.w -= lse;
        r4[i] = v;
    }
}

extern "C" void kernel_launch(void* const* d_in, const int* in_sizes, int n_in,
                              void* d_out, int out_size, void* d_ws, size_t ws_size,
                              hipStream_t stream) {
    const int*   src     = (const int*)d_in[0];
    const int*   trg     = (const int*)d_in[1];
    const int*   start   = (const int*)d_in[2];
    const float* enc_emb = (const float*)d_in[3];
    const float* enc_Wih = (const float*)d_in[4];
    const float* enc_Whh = (const float*)d_in[5];
    const float* enc_bih = (const float*)d_in[6];
    const float* enc_bhh = (const float*)d_in[7];
    const float* dec_emb = (const float*)d_in[8];
    const float* dec_Wih = (const float*)d_in[9];
    const float* dec_Whh = (const float*)d_in[10];
    const float* dec_bih = (const float*)d_in[11];
    const float* dec_bhh = (const float*)d_in[12];
    const float* lin_W   = (const float*)d_in[13];
    const float* lin_b   = (const float*)d_in[14];
    float* out = (float*)d_out;

    char* ws = (char*)d_ws;
    float*  encXW = (float*)(ws);                   // 256*4096 f32 = 4 MiB
    float*  decXW = (float*)(ws + 4194304);         // 4 MiB
    bf16_t* Hs    = (bf16_t*)(ws + 8388608);        // 256*1024 bf16 = 512 KiB
    u64*    hseq  = (u64*)(ws + 9437184);           // [512][1024] u64 = 4 MiB

    // input GEMMs (enc+dec) + hseq zeroing, one kernel, 4 dispatches total
    xw_all<<<512, 64, 0, stream>>>(src, trg, start,
                                   enc_emb, enc_Wih, enc_bih, enc_bhh,
                                   dec_emb, dec_Wih, dec_bih, dec_bhh,
                                   encXW, decXW, hseq);

    // persistent recurrence: 128 co-resident WGs, 512 steps, dataflow sync
    lstm_seq<<<NWGC, 256, 0, stream>>>(encXW, decXW, enc_Whh, dec_Whh, hseq, Hs);

    // output projection + log_softmax
    out_gemm<<<500, 256, 0, stream>>>(Hs, lin_W, lin_b, out);
    log_softmax_k<<<256, 1024, 0, stream>>>(out);
}